// Round 3
// baseline (297.478 us; speedup 1.0000x reference)
//
// R10: A-operand preprocessing. k_prep gathers x, does the fp32->bf16 hi/lo
// split ONCE (was 8x redundant in k_gemm), and writes A in gemm-fragment byte
// order (per-(chunk,stage) contiguous 32KB). k_gemm2 then stages A via
// global_load_lds (coalesced, no VALU, no VGPR round-trip), double-buffered
// LDS (80KB, 2 blocks/CU), ONE barrier per stage, next-stage loads issued
// before the MFMA block (T14). Epilogue: split-K part stores (R9). k_sum /
// k_reduce / k_sample / PRNG unchanged from R9. Fallbacks: R9 path if ws<98MB.
#include <hip/hip_runtime.h>
#include <stdint.h>

#define BATCH 256
#define NMAC  512
#define ROWF  128            // cms_prev * neur_prev
#define I_    32768
#define C_    32
#define N_    32
#define XROW  (NMAC * ROWF)  // 65536 floats per batch row
#define NCH   64             // split-K chunks (512 i each)
#define NST   16             // stages per chunk (KK=32)

typedef float  f32x4  __attribute__((ext_vector_type(4)));
typedef __bf16 bf16x8 __attribute__((ext_vector_type(8)));

__device__ __forceinline__ uint32_t f2bf_rne(float f) {
    uint32_t u = __builtin_bit_cast(uint32_t, f);
    return (u + 0x7FFFu + ((u >> 16) & 1u)) >> 16;
}

__device__ __forceinline__ void gll16(const void* g, void* l) {
    __builtin_amdgcn_global_load_lds(
        (const __attribute__((address_space(1))) uint32_t*)g,
        (__attribute__((address_space(3))) uint32_t*)l, 16, 0, 0);
}

// ---------------- per-row sums S[b] (unchanged) ----------------
__global__ __launch_bounds__(256) void k_sum(const float* __restrict__ x,
                                             const int* __restrict__ filt,
                                             float* __restrict__ S) {
    const int b = blockIdx.x;
    const int t = threadIdx.x;
    const float* xb = x + (size_t)b * XROW;
    float s = 0.f;
    for (int it = 0; it < 32; ++it) {
        int idx4 = it * 256 + t;
        int f = idx4 >> 5;
        int j4 = idx4 & 31;
        float4 v = *(const float4*)(xb + (size_t)filt[f] * ROWF + j4 * 4);
        s += v.x + v.y + v.z + v.w;
    }
    for (int o = 32; o > 0; o >>= 1) s += __shfl_down(s, o, 64);
    __shared__ float red[4];
    if ((t & 63) == 0) red[t >> 6] = s;
    __syncthreads();
    if (t == 0) S[b] = red[0] + red[1] + red[2] + red[3];
}

// ---------------- A prep: gather + hi/lo split + fragment order --------------
// grid 1024 = (chunk 64) x (stage 16), 256 thr (thread = batch row b).
// Output short index within a 16384-short block (identical to R7 afr layout):
//   (rt*2 + p)*512 + ((k>>3)*16 + (b&15))*8 + (k&7),  rt = b>>4, p = hi/lo.
__global__ __launch_bounds__(256) void k_prep(const float* __restrict__ x,
                                              const int* __restrict__ filt,
                                              unsigned short* __restrict__ prepA) {
    const int b     = threadIdx.x;
    const int chunk = blockIdx.x >> 4;
    const int st    = blockIdx.x & 15;
    const int ifull = chunk * 512 + st * 32;
    const int fidx  = filt[ifull >> 7];
    const int ioff  = ifull & 127;
    const float* src = x + (size_t)b * XROW + (size_t)fidx * ROWF + ioff;
    unsigned short* dstb = prepA + (size_t)blockIdx.x * 16384
                         + (b >> 4) * 1024 + (b & 15) * 8;
    float4 v[8];
#pragma unroll
    for (int j = 0; j < 8; ++j) v[j] = ((const float4*)src)[j];
#pragma unroll
    for (int kq = 0; kq < 4; ++kq) {
        float f[8];
        float4 a = v[kq * 2], c = v[kq * 2 + 1];
        f[0] = a.x; f[1] = a.y; f[2] = a.z; f[3] = a.w;
        f[4] = c.x; f[5] = c.y; f[6] = c.z; f[7] = c.w;
        uint32_t h[4], lo[4];
#pragma unroll
        for (int e = 0; e < 4; ++e) {
            uint32_t u0 = __builtin_bit_cast(uint32_t, f[2 * e]);
            uint32_t u1 = __builtin_bit_cast(uint32_t, f[2 * e + 1]);
            // hi = truncate-to-bf16; lo = RNE bf16 of remainder (same as R7)
            float r0 = f[2 * e]     - __builtin_bit_cast(float, u0 & 0xFFFF0000u);
            float r1 = f[2 * e + 1] - __builtin_bit_cast(float, u1 & 0xFFFF0000u);
            h[e]  = (u0 >> 16) | (u1 & 0xFFFF0000u);
            lo[e] = f2bf_rne(r0) | (f2bf_rne(r1) << 16);
        }
        *(uint4*)&dstb[kq * 128]       = make_uint4(h[0], h[1], h[2], h[3]);
        *(uint4*)&dstb[512 + kq * 128] = make_uint4(lo[0], lo[1], lo[2], lo[3]);
    }
}

// ---------------- gemm2: A via global_load_lds, dbuf LDS, 1 barrier/stage ----
// grid 512 = (c-group 8 x 4c) x (chunk 64); 256 thr / 4 waves.
// Note: the 8 blocks sharing a chunk are 64 apart in bid -> same bid%8 ->
// same XCD -> A re-reads are L2-local.
__global__ __launch_bounds__(256, 2) void k_gemm2(const unsigned short* __restrict__ prepA,
                                                  const float* __restrict__ w,
                                                  float* __restrict__ part) {
    __shared__ __align__(16) unsigned short bufA[2][16384];  // 2 x 32 KB
    __shared__ __align__(16) unsigned short bufW[2][4096];   // 2 x  8 KB

    const int t  = threadIdx.x;
    const int l  = t & 63;
    const int wv = t >> 6;
    const int chunk = blockIdx.x & 63;
    const int c0 = (blockIdx.x >> 6) * 4;

    const char* Abase = (const char*)(prepA + (size_t)chunk * NST * 16384);
    const int wn = t & 31;
    const int wc = t >> 5;

    f32x4 acc[4][8];
#pragma unroll
    for (int bt = 0; bt < 4; ++bt)
#pragma unroll
        for (int ct = 0; ct < 8; ++ct) acc[bt][ct] = f32x4{0.f, 0.f, 0.f, 0.f};

    uint32_t Wr[8];

    auto issueA = [&](int st, int bsel) {
        const char* s = Abase + (size_t)st * 32768 + wv * 1024 + l * 16;
        char* d = ((char*)&bufA[bsel][0]) + wv * 1024;
#pragma unroll
        for (int r = 0; r < 8; ++r)
            gll16(s + r * 4096, d + r * 4096);
    };
    auto loadW = [&](int st) {
        const int ifull = chunk * 512 + st * 32;
#pragma unroll
        for (int q = 0; q < 8; ++q) {
            int sl = wc + 8 * q;
            int c  = sl >> 4;
            int il = (sl & 15) * 2;
            const float* wp = w + ((size_t)(c0 + c) * I_ + ifull + il) * N_ + wn;
            uint32_t u0 = __builtin_bit_cast(uint32_t, wp[0]);
            uint32_t u1 = __builtin_bit_cast(uint32_t, wp[N_]);
            Wr[q] = (u0 >> 16) | (u1 & 0xFFFF0000u);
        }
    };
    auto storeW = [&](int bsel) {
#pragma unroll
        for (int q = 0; q < 8; ++q) {
            int sl = wc + 8 * q;
            int c  = sl >> 4;
            int il = (sl & 15) * 2;
            int lane = (il >> 3) * 16 + (wn & 15);
            int ct   = c * 2 + (wn >> 4);
            *(uint32_t*)&bufW[bsel][ct * 512 + lane * 8 + (il & 7)] = Wr[q];
        }
    };

    // prologue: stage 0 into buffer 0
    issueA(0, 0);
    loadW(0); storeW(0);
    __syncthreads();                       // drains vmcnt(0): A(0) landed

    for (int st = 0; st < NST; ++st) {
        const int cur = st & 1, nxt = cur ^ 1;
        if (st + 1 < NST) { issueA(st + 1, nxt); loadW(st + 1); }  // in flight over MFMA

        bf16x8 av[4][2];
#pragma unroll
        for (int bt = 0; bt < 4; ++bt)
#pragma unroll
            for (int p = 0; p < 2; ++p)
                av[bt][p] = *(const bf16x8*)&bufA[cur][((wv * 4 + bt) * 2 + p) * 512 + l * 8];
        bf16x8 bv[8];
#pragma unroll
        for (int ct = 0; ct < 8; ++ct)
            bv[ct] = *(const bf16x8*)&bufW[cur][ct * 512 + l * 8];
#pragma unroll
        for (int bt = 0; bt < 4; ++bt)
#pragma unroll
            for (int ct = 0; ct < 8; ++ct) {
                acc[bt][ct] = __builtin_amdgcn_mfma_f32_16x16x32_bf16(av[bt][0], bv[ct], acc[bt][ct], 0, 0, 0);
                acc[bt][ct] = __builtin_amdgcn_mfma_f32_16x16x32_bf16(av[bt][1], bv[ct], acc[bt][ct], 0, 0, 0);
            }
        if (st + 1 < NST) storeW(nxt);
        __syncthreads();                   // A(st+1) landed + W(st+1) visible + reads of cur done
    }

    // ---- epilogue: plain split-K stores (D col = lane&15, row = quad*4+reg) ----
    const int quad = l >> 4, n15 = l & 15;
    float* dst = part + (size_t)chunk * (BATCH * C_ * N_);
#pragma unroll
    for (int bt = 0; bt < 4; ++bt) {
#pragma unroll
        for (int ct = 0; ct < 8; ++ct) {
            int c = c0 + (ct >> 1);
            int n = (ct & 1) * 16 + n15;
#pragma unroll
            for (int r = 0; r < 4; ++r) {
                int b = (wv * 4 + bt) * 16 + quad * 4 + r;
                dst[((size_t)b * C_ + c) * N_ + n] = acc[bt][ct][r];
            }
        }
    }
}

// ---------------- legacy gemm (fallback paths only; R9 body) ----------------
__global__ __launch_bounds__(256, 2) void k_gemm_fb(const float* __restrict__ x,
                                                    const int* __restrict__ filt,
                                                    const float* __restrict__ w,
                                                    float* __restrict__ part,
                                                    float* __restrict__ raw,
                                                    int use_part) {
    __shared__ __align__(16) unsigned short afr[32 * 512];
    __shared__ __align__(16) unsigned short wfr[8 * 512];

    const int t  = threadIdx.x;
    const int l  = t & 63;
    const int wv = t >> 6;
    const int chunk = blockIdx.x & 63;
    const int c0 = (blockIdx.x >> 6) * 4;

    f32x4 acc[4][8];
#pragma unroll
    for (int bt = 0; bt < 4; ++bt)
#pragma unroll
        for (int ct = 0; ct < 8; ++ct) acc[bt][ct] = f32x4{0.f, 0.f, 0.f, 0.f};

    const int ar     = t >> 3;
    const int ai     = t & 7;
    const int a_quad = ai >> 1;
    const int a_j    = (ai & 1) * 4;
    const int wn = t & 31;
    const int wc = t >> 5;

    for (int st = 0; st < 16; ++st) {
        const int ifull = chunk * 512 + st * 32;
        const int fidx  = filt[ifull >> 7];
        const int ioff  = ifull & 127;
        const float* xs = x + (size_t)fidx * ROWF + ioff;

#pragma unroll
        for (int rr = 0; rr < 8; ++rr) {
            int row = rr * 32 + ar;
            float4 v = *(const float4*)(xs + (size_t)row * XROW + ai * 4);
            uint32_t u0 = __builtin_bit_cast(uint32_t, v.x);
            uint32_t u1 = __builtin_bit_cast(uint32_t, v.y);
            uint32_t u2 = __builtin_bit_cast(uint32_t, v.z);
            uint32_t u3 = __builtin_bit_cast(uint32_t, v.w);
            float l0 = v.x - __builtin_bit_cast(float, u0 & 0xFFFF0000u);
            float l1 = v.y - __builtin_bit_cast(float, u1 & 0xFFFF0000u);
            float l2 = v.z - __builtin_bit_cast(float, u2 & 0xFFFF0000u);
            float l3 = v.w - __builtin_bit_cast(float, u3 & 0xFFFF0000u);
            uint2 hp, lp;
            hp.x = (u0 >> 16) | (u1 & 0xFFFF0000u);
            hp.y = (u2 >> 16) | (u3 & 0xFFFF0000u);
            lp.x = f2bf_rne(l0) | (f2bf_rne(l1) << 16);
            lp.y = f2bf_rne(l2) | (f2bf_rne(l3) << 16);
            int rt   = row >> 4;
            int lane = a_quad * 16 + (row & 15);
            int base = (rt * 2) * 512 + lane * 8 + a_j;
            *(uint2*)&afr[base]       = hp;
            *(uint2*)&afr[base + 512] = lp;
        }
#pragma unroll
        for (int q = 0; q < 8; ++q) {
            int sl  = wc + 8 * q;
            int c   = sl >> 4;
            int il  = (sl & 15) * 2;
            const float* wp = w + ((size_t)(c0 + c) * I_ + ifull + il) * N_ + wn;
            uint32_t u0 = __builtin_bit_cast(uint32_t, wp[0]);
            uint32_t u1 = __builtin_bit_cast(uint32_t, wp[N_]);
            uint32_t pk = (u0 >> 16) | (u1 & 0xFFFF0000u);
            int lane = (il >> 3) * 16 + (wn & 15);
            int ct   = c * 2 + (wn >> 4);
            *(uint32_t*)&wfr[ct * 512 + lane * 8 + (il & 7)] = pk;
        }
        __syncthreads();

        bf16x8 av[4][2];
#pragma unroll
        for (int bt = 0; bt < 4; ++bt)
#pragma unroll
            for (int p = 0; p < 2; ++p)
                av[bt][p] = *(const bf16x8*)&afr[((wv * 4 + bt) * 2 + p) * 512 + l * 8];
        bf16x8 bv[8];
#pragma unroll
        for (int ct = 0; ct < 8; ++ct)
            bv[ct] = *(const bf16x8*)&wfr[ct * 512 + l * 8];
#pragma unroll
        for (int bt = 0; bt < 4; ++bt)
#pragma unroll
            for (int ct = 0; ct < 8; ++ct) {
                acc[bt][ct] = __builtin_amdgcn_mfma_f32_16x16x32_bf16(av[bt][0], bv[ct], acc[bt][ct], 0, 0, 0);
                acc[bt][ct] = __builtin_amdgcn_mfma_f32_16x16x32_bf16(av[bt][1], bv[ct], acc[bt][ct], 0, 0, 0);
            }
        __syncthreads();
    }

    const int quad = l >> 4, n15 = l & 15;
    if (use_part) {
        float* dst = part + (size_t)chunk * (BATCH * C_ * N_);
#pragma unroll
        for (int bt = 0; bt < 4; ++bt)
#pragma unroll
            for (int ct = 0; ct < 8; ++ct) {
                int c = c0 + (ct >> 1);
                int n = (ct & 1) * 16 + n15;
#pragma unroll
                for (int r = 0; r < 4; ++r) {
                    int b = (wv * 4 + bt) * 16 + quad * 4 + r;
                    dst[((size_t)b * C_ + c) * N_ + n] = acc[bt][ct][r];
                }
            }
    } else {
#pragma unroll
        for (int bt = 0; bt < 4; ++bt)
#pragma unroll
            for (int ct = 0; ct < 8; ++ct) {
                int c = c0 + (ct >> 1);
                int n = (ct & 1) * 16 + n15;
#pragma unroll
                for (int r = 0; r < 4; ++r) {
                    int b = (wv * 4 + bt) * 16 + quad * 4 + r;
                    atomicAdd(&raw[((size_t)b * C_ + c) * N_ + n], acc[bt][ct][r]);
                }
            }
    }
}

// ---------------- split-K reduce + fused familiarity (unchanged) -------------
__global__ __launch_bounds__(256) void k_reduce(const float* __restrict__ part,
                                                const float* __restrict__ S,
                                                float* __restrict__ raw,
                                                float* __restrict__ fam) {
    const int i4 = blockIdx.x * 256 + threadIdx.x;     // 65536 float4
    const f32x4* p = (const f32x4*)part;
    f32x4 s = f32x4{0.f, 0.f, 0.f, 0.f};
#pragma unroll 8
    for (int ch = 0; ch < NCH; ++ch) s += p[(size_t)ch * 65536 + i4];
    ((f32x4*)raw)[i4] = s;
    float m = fmaxf(fmaxf(s[0], s[1]), fmaxf(s[2], s[3]));
    m = fmaxf(m, __shfl_xor(m, 1, 64));
    m = fmaxf(m, __shfl_xor(m, 2, 64));
    m = fmaxf(m, __shfl_xor(m, 4, 64));
    int r = i4 >> 3;
    float v = ((i4 & 7) == 0) ? (m / S[r >> 5]) : 0.f;
    for (int o = 32; o > 0; o >>= 1) v += __shfl_down(v, o, 64);
    __shared__ float red[4];
    if ((threadIdx.x & 63) == 0) red[threadIdx.x >> 6] = v;
    __syncthreads();
    if (threadIdx.x == 0) atomicAdd(fam, red[0] + red[1] + red[2] + red[3]);
}

// ---------------- familiarity (atomic-fallback path only) --------------------
__global__ __launch_bounds__(256) void k_fam(const float* __restrict__ raw,
                                             const float* __restrict__ S,
                                             float* __restrict__ fam) {
    int r = blockIdx.x * 256 + threadIdx.x;
    const float4* ap = (const float4*)(raw + (size_t)r * N_);
    float m = -3.0e38f;
#pragma unroll
    for (int q = 0; q < 8; ++q) {
        float4 v = ap[q];
        m = fmaxf(m, fmaxf(fmaxf(v.x, v.y), fmaxf(v.z, v.w)));
    }
    m = m / S[r >> 5];
    for (int o = 32; o > 0; o >>= 1) m += __shfl_down(m, o, 64);
    __shared__ float red[4];
    if ((threadIdx.x & 63) == 0) red[threadIdx.x >> 6] = m;
    __syncthreads();
    if (threadIdx.x == 0) atomicAdd(fam, red[0] + red[1] + red[2] + red[3]);
}

// ---------------- Threefry-2x32-20 core (unchanged) ----------------
__device__ __forceinline__ uint32_t rotl32(uint32_t x, uint32_t r) {
    return (x << r) | (x >> (32u - r));
}
__device__ __forceinline__ void threefry(uint32_t k0, uint32_t k1,
                                         uint32_t x0, uint32_t x1,
                                         uint32_t& o0, uint32_t& o1) {
    uint32_t ks2 = k0 ^ k1 ^ 0x1BD11BDAu;
    x0 += k0; x1 += k1;
    x0 += x1; x1 = rotl32(x1, 13); x1 ^= x0;
    x0 += x1; x1 = rotl32(x1, 15); x1 ^= x0;
    x0 += x1; x1 = rotl32(x1, 26); x1 ^= x0;
    x0 += x1; x1 = rotl32(x1, 6);  x1 ^= x0;
    x0 += k1; x1 += ks2 + 1u;
    x0 += x1; x1 = rotl32(x1, 17); x1 ^= x0;
    x0 += x1; x1 = rotl32(x1, 29); x1 ^= x0;
    x0 += x1; x1 = rotl32(x1, 16); x1 ^= x0;
    x0 += x1; x1 = rotl32(x1, 24); x1 ^= x0;
    x0 += ks2; x1 += k0 + 2u;
    x0 += x1; x1 = rotl32(x1, 13); x1 ^= x0;
    x0 += x1; x1 = rotl32(x1, 15); x1 ^= x0;
    x0 += x1; x1 = rotl32(x1, 26); x1 ^= x0;
    x0 += x1; x1 = rotl32(x1, 6);  x1 ^= x0;
    x0 += k0; x1 += k1 + 3u;
    x0 += x1; x1 = rotl32(x1, 17); x1 ^= x0;
    x0 += x1; x1 = rotl32(x1, 29); x1 ^= x0;
    x0 += x1; x1 = rotl32(x1, 16); x1 ^= x0;
    x0 += x1; x1 = rotl32(x1, 24); x1 ^= x0;
    x0 += k1; x1 += ks2 + 4u;
    x0 += x1; x1 = rotl32(x1, 13); x1 ^= x0;
    x0 += x1; x1 = rotl32(x1, 15); x1 ^= x0;
    x0 += x1; x1 = rotl32(x1, 26); x1 ^= x0;
    x0 += x1; x1 = rotl32(x1, 6);  x1 ^= x0;
    x0 += ks2; x1 += k0 + 5u;
    o0 = x0; o1 = x1;
}

__device__ __forceinline__ float gumbel_of(uint32_t bits) {
    uint32_t fb = (bits >> 9) | 0x3F800000u;
    float f = __builtin_bit_cast(float, fb) - 1.0f;
    float u = f + 1.17549435e-38f;
    return -logf(-logf(u));
}

// ---------------- sample (unchanged) ----------------
__global__ __launch_bounds__(256) void k_sample(const float* __restrict__ raw,
                                                const float* __restrict__ S,
                                                const float* __restrict__ fam,
                                                int* __restrict__ out) {
    int r0 = blockIdx.x * 256 + threadIdx.x;
    int r1 = r0 + 4096;
    float avg  = fam[0] * (1.0f / 8192.0f);
    float temp = 1.0f / (avg + 1e-4f) - 1.0f;
    float sA = S[r0 >> 5], sB = S[r1 >> 5];
    const float* apA = raw + (size_t)r0 * N_;
    const float* apB = raw + (size_t)r1 * N_;

    float bestA = -3.4e38f, bestB = -3.4e38f;
    int biA = 0, biB = 0;
    for (int n = 0; n < 32; ++n) {
        uint32_t iA = (uint32_t)(r0 * 32 + n);
        uint32_t iB = (uint32_t)(r1 * 32 + n);
        uint32_t a0, a1, b0, b1;
        threefry(0u, 42u, 0u, iA, a0, a1);
        threefry(0u, 42u, 0u, iB, b0, b1);
        float vA = (apA[n] / sA) / temp + gumbel_of(a0 ^ a1);
        float vB = (apB[n] / sB) / temp + gumbel_of(b0 ^ b1);
        if (vA > bestA) { bestA = vA; biA = n; }
        if (vB > bestB) { bestB = vB; biB = n; }
    }
    int4* opA = (int4*)(out + (size_t)r0 * N_);
    int4* opB = (int4*)(out + (size_t)r1 * N_);
#pragma unroll
    for (int q = 0; q < 8; ++q) {
        int4 a, b;
        a.x = (q * 4 + 0) == biA; a.y = (q * 4 + 1) == biA;
        a.z = (q * 4 + 2) == biA; a.w = (q * 4 + 3) == biA;
        b.x = (q * 4 + 0) == biB; b.y = (q * 4 + 1) == biB;
        b.z = (q * 4 + 2) == biB; b.w = (q * 4 + 3) == biB;
        opA[q] = a; opB[q] = b;
    }
}

extern "C" void kernel_launch(void* const* d_in, const int* in_sizes, int n_in,
                              void* d_out, int out_size, void* d_ws, size_t ws_size,
                              hipStream_t stream) {
    const float* x    = (const float*)d_in[0];
    const int*   filt = (const int*)d_in[1];
    const float* w    = (const float*)d_in[2];
    int* out = (int*)d_out;

    char* ws = (char*)d_ws;
    float* raw  = (float*)ws;                          // 1 MB
    float* fam  = (float*)(ws + (1 << 20));            // 4 B
    float* S    = (float*)(ws + (1 << 20) + 128);      // 1 KB
    float* part = (float*)(ws + (2u << 20));           // 64 MB split-K partials
    unsigned short* prepA = (unsigned short*)(ws + (66u << 20)); // 32 MB

    const size_t need_part = (2u << 20) + (size_t)NCH * (BATCH * C_ * N_) * sizeof(float);
    const size_t need_prep = need_part + (size_t)NCH * NST * 16384 * sizeof(unsigned short);

    if (ws_size >= need_prep) {
        hipMemsetAsync(ws + (1 << 20), 0, 128, stream);           // fam only
        hipLaunchKernelGGL(k_prep,   dim3(1024), dim3(256), 0, stream, x, filt, prepA);
        hipLaunchKernelGGL(k_sum,    dim3(256),  dim3(256), 0, stream, x, filt, S);
        hipLaunchKernelGGL(k_gemm2,  dim3(512),  dim3(256), 0, stream, prepA, w, part);
        hipLaunchKernelGGL(k_reduce, dim3(256),  dim3(256), 0, stream, part, S, raw, fam);
        hipLaunchKernelGGL(k_sample, dim3(16),   dim3(256), 0, stream, raw, S, fam, out);
    } else if (ws_size >= need_part) {
        hipMemsetAsync(ws + (1 << 20), 0, 128, stream);
        hipLaunchKernelGGL(k_sum,    dim3(256), dim3(256), 0, stream, x, filt, S);
        hipLaunchKernelGGL(k_gemm_fb, dim3(512), dim3(256), 0, stream, x, filt, w, part, raw, 1);
        hipLaunchKernelGGL(k_reduce, dim3(256), dim3(256), 0, stream, part, S, raw, fam);
        hipLaunchKernelGGL(k_sample, dim3(16),  dim3(256), 0, stream, raw, S, fam, out);
    } else {
        hipMemsetAsync(ws, 0, (1 << 20) + 128, stream);
        hipLaunchKernelGGL(k_sum,    dim3(256), dim3(256), 0, stream, x, filt, S);
        hipLaunchKernelGGL(k_gemm_fb, dim3(512), dim3(256), 0, stream, x, filt, w, part, raw, 0);
        hipLaunchKernelGGL(k_fam,    dim3(32),  dim3(256), 0, stream, raw, S, fam);
        hipLaunchKernelGGL(k_sample, dim3(16),  dim3(256), 0, stream, raw, S, fam, out);
    }
}

// Round 4
// 296.222 us; speedup vs baseline: 1.0042x; 1.0042x over previous
//
// R11: occupancy attack. R10's ablation showed staging VALU / coalescing /
// barrier count are NOT the gemm bottleneck (gemm2 == gemm_fb); R0 counters
// (all pipes idle, occ 18%) say latency-bound at 2 blocks/CU. k_gemm3 splits
// the BATCH dim across blocks: grid 1024 = 2 b-halves x 8 c-groups x 64
// chunks, 256 thr / 4 waves, acc[2][8] (64 acc regs), A tile 16KB, LDS 24KB
// -> 4 blocks/CU = 16 waves/CU (2x latency hiding). Same per-output MFMA
// order as R7/R9 (absmax 0 preserved). k_prep path dropped (R10 regression).
// k_sum / k_reduce / k_sample / PRNG byte-identical to R9.
#include <hip/hip_runtime.h>
#include <stdint.h>

#define BATCH 256
#define NMAC  512
#define ROWF  128            // cms_prev * neur_prev
#define I_    32768
#define C_    32
#define N_    32
#define XROW  (NMAC * ROWF)  // 65536 floats per batch row
#define NCH   64             // split-K chunks (512 i each)

typedef float  f32x4  __attribute__((ext_vector_type(4)));
typedef __bf16 bf16x8 __attribute__((ext_vector_type(8)));

__device__ __forceinline__ uint32_t f2bf_rne(float f) {
    uint32_t u = __builtin_bit_cast(uint32_t, f);
    return (u + 0x7FFFu + ((u >> 16) & 1u)) >> 16;
}

// ---------------- per-row sums S[b] (unchanged) ----------------
__global__ __launch_bounds__(256) void k_sum(const float* __restrict__ x,
                                             const int* __restrict__ filt,
                                             float* __restrict__ S) {
    const int b = blockIdx.x;
    const int t = threadIdx.x;
    const float* xb = x + (size_t)b * XROW;
    float s = 0.f;
    for (int it = 0; it < 32; ++it) {
        int idx4 = it * 256 + t;
        int f = idx4 >> 5;
        int j4 = idx4 & 31;
        float4 v = *(const float4*)(xb + (size_t)filt[f] * ROWF + j4 * 4);
        s += v.x + v.y + v.z + v.w;
    }
    for (int o = 32; o > 0; o >>= 1) s += __shfl_down(s, o, 64);
    __shared__ float red[4];
    if ((t & 63) == 0) red[t >> 6] = s;
    __syncthreads();
    if (t == 0) S[b] = red[0] + red[1] + red[2] + red[3];
}

// ---------------- gemm3: batch-split for occupancy ----------------
// grid 1024: chunk = bid&63, c-group = (bid>>6)&7 (4 c each), b-half = bid>>9
// (128 rows each). 256 thr / 4 waves; per-wave output 32 rows x 128 (c,n).
// A tile 128x32 hi/lo bf16 = 16 KB; W tile 8 KB -> 24 KB LDS, acc[2][8].
// Per-output accumulation order identical to R7/R9 (bit-exact).
__global__ __launch_bounds__(256, 2) void k_gemm3(const float* __restrict__ x,
                                                  const int* __restrict__ filt,
                                                  const float* __restrict__ w,
                                                  float* __restrict__ part) {
    __shared__ __align__(16) unsigned short afr[16 * 512];  // 16 KB: 8 rt x 2 part
    __shared__ __align__(16) unsigned short wfr[8 * 512];   //  8 KB

    const int t  = threadIdx.x;
    const int l  = t & 63;
    const int wv = t >> 6;
    const int chunk = blockIdx.x & 63;
    const int c0 = ((blockIdx.x >> 6) & 7) * 4;
    const int b0 = (blockIdx.x >> 9) * 128;

    f32x4 acc[2][8];
#pragma unroll
    for (int bt = 0; bt < 2; ++bt)
#pragma unroll
        for (int ct = 0; ct < 8; ++ct) acc[bt][ct] = f32x4{0.f, 0.f, 0.f, 0.f};

    // A staging map: thread covers (local row = rr*32 + (t>>3), k = (t&7)*4..+3)
    const int ar     = t >> 3;             // 0..31
    const int ai     = t & 7;
    const int a_quad = ai >> 1;
    const int a_j    = (ai & 1) * 4;
    // W staging map
    const int wn = t & 31;
    const int wc = t >> 5;

    for (int st = 0; st < 16; ++st) {
        const int ifull = chunk * 512 + st * 32;
        const int fidx  = filt[ifull >> 7];
        const int ioff  = ifull & 127;
        const float* xs = x + (size_t)b0 * XROW + (size_t)fidx * ROWF + ioff;

        // ---- stage A: 16 KB fp32 -> split bf16 frag-order LDS ----
#pragma unroll
        for (int rr = 0; rr < 4; ++rr) {
            int row = rr * 32 + ar;        // local 0..127
            float4 v = *(const float4*)(xs + (size_t)row * XROW + ai * 4);
            uint32_t u0 = __builtin_bit_cast(uint32_t, v.x);
            uint32_t u1 = __builtin_bit_cast(uint32_t, v.y);
            uint32_t u2 = __builtin_bit_cast(uint32_t, v.z);
            uint32_t u3 = __builtin_bit_cast(uint32_t, v.w);
            // hi = truncate-to-bf16 (error absorbed by lo); lo = RNE bf16 of remainder
            float l0 = v.x - __builtin_bit_cast(float, u0 & 0xFFFF0000u);
            float l1 = v.y - __builtin_bit_cast(float, u1 & 0xFFFF0000u);
            float l2 = v.z - __builtin_bit_cast(float, u2 & 0xFFFF0000u);
            float l3 = v.w - __builtin_bit_cast(float, u3 & 0xFFFF0000u);
            uint2 hp, lp;
            hp.x = (u0 >> 16) | (u1 & 0xFFFF0000u);
            hp.y = (u2 >> 16) | (u3 & 0xFFFF0000u);
            lp.x = f2bf_rne(l0) | (f2bf_rne(l1) << 16);
            lp.y = f2bf_rne(l2) | (f2bf_rne(l3) << 16);
            int rt   = row >> 4;           // 0..7
            int lane = a_quad * 16 + (row & 15);
            int base = (rt * 2) * 512 + lane * 8 + a_j;
            *(uint2*)&afr[base]       = hp;          // part 0 (hi)
            *(uint2*)&afr[base + 512] = lp;          // part 1 (lo)
        }

        // ---- stage W: k-pair scalar loads, pack top-16s ({0,1} exact) ----
#pragma unroll
        for (int q = 0; q < 8; ++q) {
            int sl  = wc + 8 * q;
            int c   = sl >> 4;
            int il  = (sl & 15) * 2;
            const float* wp = w + ((size_t)(c0 + c) * I_ + ifull + il) * N_ + wn;
            uint32_t u0 = __builtin_bit_cast(uint32_t, wp[0]);
            uint32_t u1 = __builtin_bit_cast(uint32_t, wp[N_]);
            uint32_t pk = (u0 >> 16) | (u1 & 0xFFFF0000u);
            int lane = (il >> 3) * 16 + (wn & 15);
            int ct   = c * 2 + (wn >> 4);
            *(uint32_t*)&wfr[ct * 512 + lane * 8 + (il & 7)] = pk;
        }
        __syncthreads();

        // ---- MFMA: 2 row-tiles x 8 (c,n)-tiles x 2 parts ----
        bf16x8 av[2][2];
#pragma unroll
        for (int bt = 0; bt < 2; ++bt)
#pragma unroll
            for (int p = 0; p < 2; ++p)
                av[bt][p] = *(const bf16x8*)&afr[((wv * 2 + bt) * 2 + p) * 512 + l * 8];
        bf16x8 bv[8];
#pragma unroll
        for (int ct = 0; ct < 8; ++ct)
            bv[ct] = *(const bf16x8*)&wfr[ct * 512 + l * 8];
#pragma unroll
        for (int bt = 0; bt < 2; ++bt)
#pragma unroll
            for (int ct = 0; ct < 8; ++ct) {
                acc[bt][ct] = __builtin_amdgcn_mfma_f32_16x16x32_bf16(av[bt][0], bv[ct], acc[bt][ct], 0, 0, 0);
                acc[bt][ct] = __builtin_amdgcn_mfma_f32_16x16x32_bf16(av[bt][1], bv[ct], acc[bt][ct], 0, 0, 0);
            }
        __syncthreads();
    }

    // ---- epilogue: split-K stores (D col = lane&15, row = quad*4 + reg) ----
    const int quad = l >> 4, n15 = l & 15;
    float* dst = part + (size_t)chunk * (BATCH * C_ * N_);
#pragma unroll
    for (int bt = 0; bt < 2; ++bt) {
#pragma unroll
        for (int ct = 0; ct < 8; ++ct) {
            int c = c0 + (ct >> 1);
            int n = (ct & 1) * 16 + n15;
#pragma unroll
            for (int r = 0; r < 4; ++r) {
                int b = b0 + (wv * 2 + bt) * 16 + quad * 4 + r;
                dst[((size_t)b * C_ + c) * N_ + n] = acc[bt][ct][r];
            }
        }
    }
}

// ---------------- legacy gemm (atomic fallback only; R9 body) ----------------
__global__ __launch_bounds__(256, 2) void k_gemm_fb(const float* __restrict__ x,
                                                    const int* __restrict__ filt,
                                                    const float* __restrict__ w,
                                                    float* __restrict__ raw) {
    __shared__ __align__(16) unsigned short afr[32 * 512];
    __shared__ __align__(16) unsigned short wfr[8 * 512];

    const int t  = threadIdx.x;
    const int l  = t & 63;
    const int wv = t >> 6;
    const int chunk = blockIdx.x & 63;
    const int c0 = (blockIdx.x >> 6) * 4;

    f32x4 acc[4][8];
#pragma unroll
    for (int bt = 0; bt < 4; ++bt)
#pragma unroll
        for (int ct = 0; ct < 8; ++ct) acc[bt][ct] = f32x4{0.f, 0.f, 0.f, 0.f};

    const int ar     = t >> 3;
    const int ai     = t & 7;
    const int a_quad = ai >> 1;
    const int a_j    = (ai & 1) * 4;
    const int wn = t & 31;
    const int wc = t >> 5;

    for (int st = 0; st < 16; ++st) {
        const int ifull = chunk * 512 + st * 32;
        const int fidx  = filt[ifull >> 7];
        const int ioff  = ifull & 127;
        const float* xs = x + (size_t)fidx * ROWF + ioff;

#pragma unroll
        for (int rr = 0; rr < 8; ++rr) {
            int row = rr * 32 + ar;
            float4 v = *(const float4*)(xs + (size_t)row * XROW + ai * 4);
            uint32_t u0 = __builtin_bit_cast(uint32_t, v.x);
            uint32_t u1 = __builtin_bit_cast(uint32_t, v.y);
            uint32_t u2 = __builtin_bit_cast(uint32_t, v.z);
            uint32_t u3 = __builtin_bit_cast(uint32_t, v.w);
            float l0 = v.x - __builtin_bit_cast(float, u0 & 0xFFFF0000u);
            float l1 = v.y - __builtin_bit_cast(float, u1 & 0xFFFF0000u);
            float l2 = v.z - __builtin_bit_cast(float, u2 & 0xFFFF0000u);
            float l3 = v.w - __builtin_bit_cast(float, u3 & 0xFFFF0000u);
            uint2 hp, lp;
            hp.x = (u0 >> 16) | (u1 & 0xFFFF0000u);
            hp.y = (u2 >> 16) | (u3 & 0xFFFF0000u);
            lp.x = f2bf_rne(l0) | (f2bf_rne(l1) << 16);
            lp.y = f2bf_rne(l2) | (f2bf_rne(l3) << 16);
            int rt   = row >> 4;
            int lane = a_quad * 16 + (row & 15);
            int base = (rt * 2) * 512 + lane * 8 + a_j;
            *(uint2*)&afr[base]       = hp;
            *(uint2*)&afr[base + 512] = lp;
        }
#pragma unroll
        for (int q = 0; q < 8; ++q) {
            int sl  = wc + 8 * q;
            int c   = sl >> 4;
            int il  = (sl & 15) * 2;
            const float* wp = w + ((size_t)(c0 + c) * I_ + ifull + il) * N_ + wn;
            uint32_t u0 = __builtin_bit_cast(uint32_t, wp[0]);
            uint32_t u1 = __builtin_bit_cast(uint32_t, wp[N_]);
            uint32_t pk = (u0 >> 16) | (u1 & 0xFFFF0000u);
            int lane = (il >> 3) * 16 + (wn & 15);
            int ct   = c * 2 + (wn >> 4);
            *(uint32_t*)&wfr[ct * 512 + lane * 8 + (il & 7)] = pk;
        }
        __syncthreads();

        bf16x8 av[4][2];
#pragma unroll
        for (int bt = 0; bt < 4; ++bt)
#pragma unroll
            for (int p = 0; p < 2; ++p)
                av[bt][p] = *(const bf16x8*)&afr[((wv * 4 + bt) * 2 + p) * 512 + l * 8];
        bf16x8 bv[8];
#pragma unroll
        for (int ct = 0; ct < 8; ++ct)
            bv[ct] = *(const bf16x8*)&wfr[ct * 512 + l * 8];
#pragma unroll
        for (int bt = 0; bt < 4; ++bt)
#pragma unroll
            for (int ct = 0; ct < 8; ++ct) {
                acc[bt][ct] = __builtin_amdgcn_mfma_f32_16x16x32_bf16(av[bt][0], bv[ct], acc[bt][ct], 0, 0, 0);
                acc[bt][ct] = __builtin_amdgcn_mfma_f32_16x16x32_bf16(av[bt][1], bv[ct], acc[bt][ct], 0, 0, 0);
            }
        __syncthreads();
    }

    const int quad = l >> 4, n15 = l & 15;
#pragma unroll
    for (int bt = 0; bt < 4; ++bt)
#pragma unroll
        for (int ct = 0; ct < 8; ++ct) {
            int c = c0 + (ct >> 1);
            int n = (ct & 1) * 16 + n15;
#pragma unroll
            for (int r = 0; r < 4; ++r) {
                int b = (wv * 4 + bt) * 16 + quad * 4 + r;
                atomicAdd(&raw[((size_t)b * C_ + c) * N_ + n], acc[bt][ct][r]);
            }
        }
}

// ---------------- split-K reduce + fused familiarity (unchanged) -------------
__global__ __launch_bounds__(256) void k_reduce(const float* __restrict__ part,
                                                const float* __restrict__ S,
                                                float* __restrict__ raw,
                                                float* __restrict__ fam) {
    const int i4 = blockIdx.x * 256 + threadIdx.x;     // 65536 float4
    const f32x4* p = (const f32x4*)part;
    f32x4 s = f32x4{0.f, 0.f, 0.f, 0.f};
#pragma unroll 8
    for (int ch = 0; ch < NCH; ++ch) s += p[(size_t)ch * 65536 + i4];
    ((f32x4*)raw)[i4] = s;
    float m = fmaxf(fmaxf(s[0], s[1]), fmaxf(s[2], s[3]));
    m = fmaxf(m, __shfl_xor(m, 1, 64));
    m = fmaxf(m, __shfl_xor(m, 2, 64));
    m = fmaxf(m, __shfl_xor(m, 4, 64));
    int r = i4 >> 3;
    float v = ((i4 & 7) == 0) ? (m / S[r >> 5]) : 0.f;
    for (int o = 32; o > 0; o >>= 1) v += __shfl_down(v, o, 64);
    __shared__ float red[4];
    if ((threadIdx.x & 63) == 0) red[threadIdx.x >> 6] = v;
    __syncthreads();
    if (threadIdx.x == 0) atomicAdd(fam, red[0] + red[1] + red[2] + red[3]);
}

// ---------------- familiarity (atomic-fallback path only) --------------------
__global__ __launch_bounds__(256) void k_fam(const float* __restrict__ raw,
                                             const float* __restrict__ S,
                                             float* __restrict__ fam) {
    int r = blockIdx.x * 256 + threadIdx.x;
    const float4* ap = (const float4*)(raw + (size_t)r * N_);
    float m = -3.0e38f;
#pragma unroll
    for (int q = 0; q < 8; ++q) {
        float4 v = ap[q];
        m = fmaxf(m, fmaxf(fmaxf(v.x, v.y), fmaxf(v.z, v.w)));
    }
    m = m / S[r >> 5];
    for (int o = 32; o > 0; o >>= 1) m += __shfl_down(m, o, 64);
    __shared__ float red[4];
    if ((threadIdx.x & 63) == 0) red[threadIdx.x >> 6] = m;
    __syncthreads();
    if (threadIdx.x == 0) atomicAdd(fam, red[0] + red[1] + red[2] + red[3]);
}

// ---------------- Threefry-2x32-20 core (unchanged) ----------------
__device__ __forceinline__ uint32_t rotl32(uint32_t x, uint32_t r) {
    return (x << r) | (x >> (32u - r));
}
__device__ __forceinline__ void threefry(uint32_t k0, uint32_t k1,
                                         uint32_t x0, uint32_t x1,
                                         uint32_t& o0, uint32_t& o1) {
    uint32_t ks2 = k0 ^ k1 ^ 0x1BD11BDAu;
    x0 += k0; x1 += k1;
    x0 += x1; x1 = rotl32(x1, 13); x1 ^= x0;
    x0 += x1; x1 = rotl32(x1, 15); x1 ^= x0;
    x0 += x1; x1 = rotl32(x1, 26); x1 ^= x0;
    x0 += x1; x1 = rotl32(x1, 6);  x1 ^= x0;
    x0 += k1; x1 += ks2 + 1u;
    x0 += x1; x1 = rotl32(x1, 17); x1 ^= x0;
    x0 += x1; x1 = rotl32(x1, 29); x1 ^= x0;
    x0 += x1; x1 = rotl32(x1, 16); x1 ^= x0;
    x0 += x1; x1 = rotl32(x1, 24); x1 ^= x0;
    x0 += ks2; x1 += k0 + 2u;
    x0 += x1; x1 = rotl32(x1, 13); x1 ^= x0;
    x0 += x1; x1 = rotl32(x1, 15); x1 ^= x0;
    x0 += x1; x1 = rotl32(x1, 26); x1 ^= x0;
    x0 += x1; x1 = rotl32(x1, 6);  x1 ^= x0;
    x0 += k0; x1 += k1 + 3u;
    x0 += x1; x1 = rotl32(x1, 17); x1 ^= x0;
    x0 += x1; x1 = rotl32(x1, 29); x1 ^= x0;
    x0 += x1; x1 = rotl32(x1, 16); x1 ^= x0;
    x0 += x1; x1 = rotl32(x1, 24); x1 ^= x0;
    x0 += k1; x1 += ks2 + 4u;
    x0 += x1; x1 = rotl32(x1, 13); x1 ^= x0;
    x0 += x1; x1 = rotl32(x1, 15); x1 ^= x0;
    x0 += x1; x1 = rotl32(x1, 26); x1 ^= x0;
    x0 += x1; x1 = rotl32(x1, 6);  x1 ^= x0;
    x0 += ks2; x1 += k0 + 5u;
    o0 = x0; o1 = x1;
}

__device__ __forceinline__ float gumbel_of(uint32_t bits) {
    uint32_t fb = (bits >> 9) | 0x3F800000u;
    float f = __builtin_bit_cast(float, fb) - 1.0f;
    float u = f + 1.17549435e-38f;
    return -logf(-logf(u));
}

// ---------------- sample (unchanged) ----------------
__global__ __launch_bounds__(256) void k_sample(const float* __restrict__ raw,
                                                const float* __restrict__ S,
                                                const float* __restrict__ fam,
                                                int* __restrict__ out) {
    int r0 = blockIdx.x * 256 + threadIdx.x;
    int r1 = r0 + 4096;
    float avg  = fam[0] * (1.0f / 8192.0f);
    float temp = 1.0f / (avg + 1e-4f) - 1.0f;
    float sA = S[r0 >> 5], sB = S[r1 >> 5];
    const float* apA = raw + (size_t)r0 * N_;
    const float* apB = raw + (size_t)r1 * N_;

    float bestA = -3.4e38f, bestB = -3.4e38f;
    int biA = 0, biB = 0;
    for (int n = 0; n < 32; ++n) {
        uint32_t iA = (uint32_t)(r0 * 32 + n);
        uint32_t iB = (uint32_t)(r1 * 32 + n);
        uint32_t a0, a1, b0, b1;
        threefry(0u, 42u, 0u, iA, a0, a1);
        threefry(0u, 42u, 0u, iB, b0, b1);
        float vA = (apA[n] / sA) / temp + gumbel_of(a0 ^ a1);
        float vB = (apB[n] / sB) / temp + gumbel_of(b0 ^ b1);
        if (vA > bestA) { bestA = vA; biA = n; }
        if (vB > bestB) { bestB = vB; biB = n; }
    }
    int4* opA = (int4*)(out + (size_t)r0 * N_);
    int4* opB = (int4*)(out + (size_t)r1 * N_);
#pragma unroll
    for (int q = 0; q < 8; ++q) {
        int4 a, b;
        a.x = (q * 4 + 0) == biA; a.y = (q * 4 + 1) == biA;
        a.z = (q * 4 + 2) == biA; a.w = (q * 4 + 3) == biA;
        b.x = (q * 4 + 0) == biB; b.y = (q * 4 + 1) == biB;
        b.z = (q * 4 + 2) == biB; b.w = (q * 4 + 3) == biB;
        opA[q] = a; opB[q] = b;
    }
}

extern "C" void kernel_launch(void* const* d_in, const int* in_sizes, int n_in,
                              void* d_out, int out_size, void* d_ws, size_t ws_size,
                              hipStream_t stream) {
    const float* x    = (const float*)d_in[0];
    const int*   filt = (const int*)d_in[1];
    const float* w    = (const float*)d_in[2];
    int* out = (int*)d_out;

    char* ws = (char*)d_ws;
    float* raw  = (float*)ws;                          // 1 MB
    float* fam  = (float*)(ws + (1 << 20));            // 4 B
    float* S    = (float*)(ws + (1 << 20) + 128);      // 1 KB
    float* part = (float*)(ws + (2u << 20));           // 64 MB split-K partials

    const size_t need_part = (2u << 20) + (size_t)NCH * (BATCH * C_ * N_) * sizeof(float);

    if (ws_size >= need_part) {
        hipMemsetAsync(ws + (1 << 20), 0, 128, stream);           // fam only
        hipLaunchKernelGGL(k_sum,    dim3(256),  dim3(256), 0, stream, x, filt, S);
        hipLaunchKernelGGL(k_gemm3,  dim3(1024), dim3(256), 0, stream, x, filt, w, part);
        hipLaunchKernelGGL(k_reduce, dim3(256),  dim3(256), 0, stream, part, S, raw, fam);
        hipLaunchKernelGGL(k_sample, dim3(16),   dim3(256), 0, stream, raw, S, fam, out);
    } else {
        hipMemsetAsync(ws, 0, (1 << 20) + 128, stream);           // raw + fam
        hipLaunchKernelGGL(k_sum,    dim3(256), dim3(256), 0, stream, x, filt, S);
        hipLaunchKernelGGL(k_gemm_fb, dim3(512), dim3(256), 0, stream, x, filt, w, raw);
        hipLaunchKernelGGL(k_fam,    dim3(32),  dim3(256), 0, stream, raw, S, fam);
        hipLaunchKernelGGL(k_sample, dim3(16),  dim3(256), 0, stream, raw, S, fam, out);
    }
}